// Round 4
// baseline (729.429 us; speedup 1.0000x reference)
//
#include <hip/hip_runtime.h>

static constexpr int B_ = 2048;
static constexpr int T_ = 2048;
static constexpr int I_ = 9;
static constexpr int H_ = 16;

__device__ __forceinline__ float f_exp2(float x) {
#if __has_builtin(__builtin_amdgcn_exp2f)
  return __builtin_amdgcn_exp2f(x);
#else
  float r; asm volatile("v_exp_f32 %0, %1" : "=v"(r) : "v"(x)); return r;
#endif
}
__device__ __forceinline__ float f_rcp(float x) {
#if __has_builtin(__builtin_amdgcn_rcpf)
  return __builtin_amdgcn_rcpf(x);
#else
  float r; asm volatile("v_rcp_f32 %0, %1" : "=v"(r) : "v"(x)); return r;
#endif
}
// broadcast float from lane `l` (wave-uniform index) via v_readlane
__device__ __forceinline__ float rlane(float v, int l) {
  return __builtin_bit_cast(float,
      __builtin_amdgcn_readlane(__builtin_bit_cast(int, v), l));
}
// DPP quad_perm broadcast: every lane gets value of lane (l & ~3) + SEL
template <int SEL>
__device__ __forceinline__ float quad_bcast(float v) {
  constexpr int ctrl = SEL * 0x55;
  return __builtin_bit_cast(float, __builtin_amdgcn_update_dpp(
      0, __builtin_bit_cast(int, v), ctrl, 0xF, 0xF, true));
}

// non-volatile register pin: value becomes asm output -> cannot be remat'd
#define PIN(v) asm("" : "+v"(v))

#define DO8(M) M(0) M(1) M(2) M(3) M(4) M(5) M(6) M(7)

// 9-term input projection for step (sb+j), element X (xA/xB), result name Xp
#define PROJ9(Xp, X, sj)                                   \
  float Xp;                                                \
  {                                                        \
    float p0 = fmaf(rlane(X##0, (sj)), wi0, bs);           \
    float p1 = rlane(X##1, (sj)) * wi1;                    \
    float p2 = rlane(X##2, (sj)) * wi2;                    \
    p0 = fmaf(rlane(X##3, (sj)), wi3, p0);                 \
    p1 = fmaf(rlane(X##4, (sj)), wi4, p1);                 \
    p2 = fmaf(rlane(X##5, (sj)), wi5, p2);                 \
    p0 = fmaf(rlane(X##6, (sj)), wi6, p0);                 \
    p1 = fmaf(rlane(X##7, (sj)), wi7, p1);                 \
    p2 = fmaf(rlane(X##8, (sj)), wi8, p2);                 \
    Xp = p0 + (p1 + p2);                                   \
  }

// one LSTM step for one element; h,cs,hf updated in place; xp = x-proj+bias'
#define LSTEP(h, cs, hf, xp, lm1, tcur)                    \
  {                                                        \
    float a0 = fmaf(rlane(h, 0), wh0, xp);                 \
    float a1 = rlane(h, 4) * wh1;                          \
    float a2 = rlane(h, 8) * wh2;                          \
    float a3 = rlane(h, 12) * wh3;                         \
    a0 = fmaf(rlane(h, 16), wh4, a0);                      \
    a1 = fmaf(rlane(h, 20), wh5, a1);                      \
    a2 = fmaf(rlane(h, 24), wh6, a2);                      \
    a3 = fmaf(rlane(h, 28), wh7, a3);                      \
    a0 = fmaf(rlane(h, 32), wh8, a0);                      \
    a1 = fmaf(rlane(h, 36), wh9, a1);                      \
    a2 = fmaf(rlane(h, 40), wh10, a2);                     \
    a3 = fmaf(rlane(h, 44), wh11, a3);                     \
    a0 = fmaf(rlane(h, 48), wh12, a0);                     \
    a1 = fmaf(rlane(h, 52), wh13, a1);                     \
    a2 = fmaf(rlane(h, 56), wh14, a2);                     \
    a3 = fmaf(rlane(h, 60), wh15, a3);                     \
    float aa = (a0 + a1) + (a2 + a3);                      \
    float e = f_exp2(aa);                                  \
    float r = f_rcp(1.0f + e);                             \
    float act = fmaf(m2c, r, a2c);                         \
    float iv = quad_bcast<0>(act);                         \
    float gv = quad_bcast<2>(act);                         \
    float fv = quad_bcast<1>(act);                         \
    float ov = quad_bcast<3>(act);                         \
    cs = fmaf(fv, cs, iv * gv);                            \
    float e2 = f_exp2(cs);                                 \
    float r2 = f_rcp(1.0f + e2);                           \
    h = fmaf(ov + ov, r2, -ov);                            \
    hf = ((tcur) == (lm1)) ? h : hf;                       \
  }

__global__ __launch_bounds__(256)
__attribute__((amdgpu_waves_per_eu(1, 1)))
void ParityLSTM_kernel(
    const float* __restrict__ x, const int* __restrict__ x_lens,
    const float* __restrict__ W_ih, const float* __restrict__ W_hh,
    const float* __restrict__ b_ih, const float* __restrict__ b_hh,
    const float* __restrict__ W_lin, const float* __restrict__ b_lin,
    float* __restrict__ out) {
  const int lane = threadIdx.x & 63;
  const int wave = threadIdx.x >> 6;
  const int wg = blockIdx.x * 4 + wave;  // 1024 waves; 2 batch elements each
  const int bA = 2 * wg;
  const int bB = 2 * wg + 1;

  // interleaved gate layout: lane = (m << 2) | q ; q: 0=i 1=f 2=g 3=o
  const int q = lane & 3;
  const int m = lane >> 2;
  const int g_id = q * H_ + m;

  constexpr float kT = -2.8853900817779268f;  // -2/ln2
  constexpr float kS = -1.4426950408889634f;  // -1/ln2
  const bool isG = (q == 2);
  const float sc1 = isG ? kT : kS;
  const float m2c = isG ? (2.0f * kT) : 1.0f;  // g-lane emits kT*tanh
  const float a2c = isG ? (-kT) : 0.0f;

  // ---- weights: shared by both elements, pre-scaled, named, pinned ----
#define LDWH(k) float wh##k = W_hh[g_id * H_ + k] * sc1;
  LDWH(0) LDWH(1) LDWH(2) LDWH(3) LDWH(4) LDWH(5) LDWH(6) LDWH(7)
  LDWH(8) LDWH(9) LDWH(10) LDWH(11) LDWH(12) LDWH(13) LDWH(14) LDWH(15)
#define LDWI(k) float wi##k = W_ih[g_id * I_ + k] * sc1;
  LDWI(0) LDWI(1) LDWI(2) LDWI(3) LDWI(4) LDWI(5) LDWI(6) LDWI(7) LDWI(8)
  float bs = (b_ih[g_id] + b_hh[g_id]) * sc1;
#define PINWH(k) PIN(wh##k);
  PINWH(0) PINWH(1) PINWH(2) PINWH(3) PINWH(4) PINWH(5) PINWH(6) PINWH(7)
  PINWH(8) PINWH(9) PINWH(10) PINWH(11) PINWH(12) PINWH(13) PINWH(14) PINWH(15)
#define PINWI(k) PIN(wi##k);
  PINWI(0) PINWI(1) PINWI(2) PINWI(3) PINWI(4) PINWI(5) PINWI(6) PINWI(7)
  PINWI(8)
  PIN(bs);

  const int lA1 = __builtin_amdgcn_readfirstlane(x_lens[bA]) - 1;
  const int lB1 = __builtin_amdgcn_readfirstlane(x_lens[bB]) - 1;
  const int maxlen = (lA1 > lB1 ? lA1 : lB1) + 1;

  const float* xbA = x + (size_t)bA * T_ * I_;
  const float* xbB = x + (size_t)bB * T_ * I_;

  float hA = 0.f, csA = 0.f, hAf = 0.f;
  float hB = 0.f, csB = 0.f, hBf = 0.f;

  // stage chunk 0: lane tt holds x[tt][0..8]
#define LD9(dst, p) \
  float dst##0 = (p)[0], dst##1 = (p)[1], dst##2 = (p)[2], dst##3 = (p)[3], \
        dst##4 = (p)[4], dst##5 = (p)[5], dst##6 = (p)[6], dst##7 = (p)[7], \
        dst##8 = (p)[8];
  const float* p0A = xbA + (size_t)lane * I_;
  const float* p0B = xbB + (size_t)lane * I_;
  LD9(xA, p0A)
  LD9(xB, p0B)

  for (int t0 = 0; t0 < maxlen; t0 += 64) {
#define PINX(k) PIN(xA##k); PIN(xB##k);
    PINX(0) PINX(1) PINX(2) PINX(3) PINX(4) PINX(5) PINX(6) PINX(7) PINX(8)
    // prefetch next chunk (address-clamped; off the dependence chain)
    int tpf = t0 + 64 + lane;
    if (tpf > T_ - 1) tpf = T_ - 1;
    const float* pA = xbA + (size_t)tpf * I_;
    const float* pB = xbB + (size_t)tpf * I_;
    LD9(nA, pA)
    LD9(nB, pB)

#pragma unroll 1
    for (int sb = 0; sb < 64; sb += 8) {
      // x-projections for 8 steps x 2 elements (off-chain, named scalars)
#define PROJPAIR(j) PROJ9(xpA##j, xA, sb + j) PROJ9(xpB##j, xB, sb + j)
      DO8(PROJPAIR)
      // the sequential chains; A and B interleave in the issue stream
#define STEPPAIR(j)                                        \
      {                                                    \
        const int tc = t0 + sb + j;                        \
        LSTEP(hA, csA, hAf, xpA##j, lA1, tc)               \
        LSTEP(hB, csB, hBf, xpB##j, lB1, tc)               \
      }
      DO8(STEPPAIR)
#undef PROJPAIR
#undef STEPPAIR
    }
    // rotate staging registers (pure renames)
#define ROT9(a, b) \
  a##0 = b##0; a##1 = b##1; a##2 = b##2; a##3 = b##3; a##4 = b##4; \
  a##5 = b##5; a##6 = b##6; a##7 = b##7; a##8 = b##8;
    ROT9(xA, nA)
    ROT9(xB, nB)
  }

  // epilogue: out[b][j] = sum_m h[m] * W_lin[j][m] + b_lin[j]
  const float wl = (q < 2) ? W_lin[q * H_ + m] : 0.0f;
  float pa = hAf * wl;
  float pb = hBf * wl;
  pa += __shfl_xor(pa, 4, 64);
  pa += __shfl_xor(pa, 8, 64);
  pa += __shfl_xor(pa, 16, 64);
  pa += __shfl_xor(pa, 32, 64);
  pb += __shfl_xor(pb, 4, 64);
  pb += __shfl_xor(pb, 8, 64);
  pb += __shfl_xor(pb, 16, 64);
  pb += __shfl_xor(pb, 32, 64);
  if (lane < 2) {
    const float bl = b_lin[lane];
    out[2 * bA + lane] = pa + bl;
    out[2 * bB + lane] = pb + bl;
  }
}

extern "C" void kernel_launch(void* const* d_in, const int* in_sizes, int n_in,
                              void* d_out, int out_size, void* d_ws,
                              size_t ws_size, hipStream_t stream) {
  const float* x = (const float*)d_in[0];
  const int* x_lens = (const int*)d_in[1];
  const float* W_ih = (const float*)d_in[2];
  const float* W_hh = (const float*)d_in[3];
  const float* b_ih = (const float*)d_in[4];
  const float* b_hh = (const float*)d_in[5];
  const float* W_lin = (const float*)d_in[6];
  const float* b_lin = (const float*)d_in[7];
  float* out = (float*)d_out;

  dim3 grid(B_ / 8);   // 256 blocks, 1 per CU
  dim3 block(256);     // 4 waves/block = 1 wave/SIMD; 2 batch elems per wave
  ParityLSTM_kernel<<<grid, block, 0, stream>>>(x, x_lens, W_ih, W_hh, b_ih,
                                                b_hh, W_lin, b_lin, out);
}

// Round 5
// 720.081 us; speedup vs baseline: 1.0130x; 1.0130x over previous
//
#include <hip/hip_runtime.h>

static constexpr int B_ = 2048;
static constexpr int T_ = 2048;
static constexpr int I_ = 9;
static constexpr int H_ = 16;

__device__ __forceinline__ float f_exp2(float x) {
#if __has_builtin(__builtin_amdgcn_exp2f)
  return __builtin_amdgcn_exp2f(x);
#else
  float r; asm volatile("v_exp_f32 %0, %1" : "=v"(r) : "v"(x)); return r;
#endif
}
__device__ __forceinline__ float f_rcp(float x) {
#if __has_builtin(__builtin_amdgcn_rcpf)
  return __builtin_amdgcn_rcpf(x);
#else
  float r; asm volatile("v_rcp_f32 %0, %1" : "=v"(r) : "v"(x)); return r;
#endif
}
// broadcast float from lane `l` (wave-uniform index) via v_readlane
__device__ __forceinline__ float rlane(float v, int l) {
  return __builtin_bit_cast(float,
      __builtin_amdgcn_readlane(__builtin_bit_cast(int, v), l));
}
// DPP quad_perm broadcast: every lane gets value of lane (l & ~3) + SEL
template <int SEL>
__device__ __forceinline__ float quad_bcast(float v) {
  constexpr int ctrl = SEL * 0x55;
  return __builtin_bit_cast(float, __builtin_amdgcn_update_dpp(
      0, __builtin_bit_cast(int, v), ctrl, 0xF, 0xF, true));
}
// non-volatile register pin: value becomes asm output -> cannot be remat'd
#define PIN(v) asm("" : "+v"(v))

__global__ __launch_bounds__(64, 1) void ParityLSTM_kernel(
    const float* __restrict__ x, const int* __restrict__ x_lens,
    const float* __restrict__ W_ih, const float* __restrict__ W_hh,
    const float* __restrict__ b_ih, const float* __restrict__ b_hh,
    const float* __restrict__ W_lin, const float* __restrict__ b_lin,
    float* __restrict__ out) {
  const int lane = threadIdx.x & 63;
  const int b = blockIdx.x;  // one batch element per (single-wave) block

  // interleaved gate layout: lane = (m << 2) | q ; q: 0=i 1=f 2=g 3=o
  const int q = lane & 3;
  const int m = lane >> 2;
  const int g_id = q * H_ + m;

  constexpr float kT = -2.8853900817779268f;  // -2/ln2
  constexpr float kS = -1.4426950408889634f;  // -1/ln2
  const bool isG = (q == 2);
  const float sc1 = isG ? kT : kS;
  const float m2c = isG ? (2.0f * kT) : 1.0f;  // g-lane emits kT*tanh
  const float a2c = isG ? (-kT) : 0.0f;

  // ---- weights: pre-scaled by sc1, named scalars, pinned in VGPRs ----
#define LDWH(k) float wh##k = W_hh[g_id * H_ + k] * sc1;
  LDWH(0) LDWH(1) LDWH(2) LDWH(3) LDWH(4) LDWH(5) LDWH(6) LDWH(7)
  LDWH(8) LDWH(9) LDWH(10) LDWH(11) LDWH(12) LDWH(13) LDWH(14) LDWH(15)
#define LDWI(k) float wi##k = W_ih[g_id * I_ + k] * sc1;
  LDWI(0) LDWI(1) LDWI(2) LDWI(3) LDWI(4) LDWI(5) LDWI(6) LDWI(7) LDWI(8)
  float bs = (b_ih[g_id] + b_hh[g_id]) * sc1;
#define PINWH(k) PIN(wh##k);
  PINWH(0) PINWH(1) PINWH(2) PINWH(3) PINWH(4) PINWH(5) PINWH(6) PINWH(7)
  PINWH(8) PINWH(9) PINWH(10) PINWH(11) PINWH(12) PINWH(13) PINWH(14)
  PINWH(15)
#define PINWI(k) PIN(wi##k);
  PINWI(0) PINWI(1) PINWI(2) PINWI(3) PINWI(4) PINWI(5) PINWI(6) PINWI(7)
  PINWI(8)
  PIN(bs);

  const int len = __builtin_amdgcn_readfirstlane(x_lens[b]);
  const float* xb = x + (size_t)b * T_ * I_;

  float h = 0.0f, cs = 0.0f;  // cs = kT * c (scaled cell state)

  // stage chunk 0: lane tt holds x[tt][0..8] (named scalars)
#define LD9(dst, p)                                                          \
  float dst##0 = (p)[0], dst##1 = (p)[1], dst##2 = (p)[2], dst##3 = (p)[3], \
        dst##4 = (p)[4], dst##5 = (p)[5], dst##6 = (p)[6], dst##7 = (p)[7], \
        dst##8 = (p)[8];
  const float* p0 = xb + (size_t)lane * I_;
  LD9(xc, p0)

  for (int t0 = 0; t0 < len; t0 += 64) {
#define PINX(k) PIN(xc##k);
    PINX(0) PINX(1) PINX(2) PINX(3) PINX(4) PINX(5) PINX(6) PINX(7) PINX(8)
    // prefetch next chunk (off the dependence chain)
    const bool more = (t0 + 64) < len;
    float nx0, nx1, nx2, nx3, nx4, nx5, nx6, nx7, nx8;
    if (more) {
      const float* pn = xb + (size_t)(t0 + 64 + lane) * I_;
      nx0 = pn[0]; nx1 = pn[1]; nx2 = pn[2]; nx3 = pn[3]; nx4 = pn[4];
      nx5 = pn[5]; nx6 = pn[6]; nx7 = pn[7]; nx8 = pn[8];
    }
    const int ns = min(64, len - t0);
#pragma unroll 4
    for (int s = 0; s < ns; ++s) {
      // x-projection (scaled): bias' + x_t @ wih'   [9 rl + 9 fma]
      float ap = fmaf(rlane(xc0, s), wi0, bs);
      ap = fmaf(rlane(xc1, s), wi1, ap);
      ap = fmaf(rlane(xc2, s), wi2, ap);
      ap = fmaf(rlane(xc3, s), wi3, ap);
      ap = fmaf(rlane(xc4, s), wi4, ap);
      ap = fmaf(rlane(xc5, s), wi5, ap);
      ap = fmaf(rlane(xc6, s), wi6, ap);
      ap = fmaf(rlane(xc7, s), wi7, ap);
      ap = fmaf(rlane(xc8, s), wi8, ap);
      // recurrent dot: h[k] lives (quad-uniform) at lane 4k  [16 rl + 16 fma]
      float ad = rlane(h, 0) * wh0;
      ad = fmaf(rlane(h, 4), wh1, ad);
      ad = fmaf(rlane(h, 8), wh2, ad);
      ad = fmaf(rlane(h, 12), wh3, ad);
      ad = fmaf(rlane(h, 16), wh4, ad);
      ad = fmaf(rlane(h, 20), wh5, ad);
      ad = fmaf(rlane(h, 24), wh6, ad);
      ad = fmaf(rlane(h, 28), wh7, ad);
      ad = fmaf(rlane(h, 32), wh8, ad);
      ad = fmaf(rlane(h, 36), wh9, ad);
      ad = fmaf(rlane(h, 40), wh10, ad);
      ad = fmaf(rlane(h, 44), wh11, ad);
      ad = fmaf(rlane(h, 48), wh12, ad);
      ad = fmaf(rlane(h, 52), wh13, ad);
      ad = fmaf(rlane(h, 56), wh14, ad);
      ad = fmaf(rlane(h, 60), wh15, ad);
      const float aa = ap + ad;

      // activation: sigmoid for i,f,o ; kT*tanh for g — branchless
      const float e = f_exp2(aa);
      const float r = f_rcp(1.0f + e);
      const float act = fmaf(m2c, r, a2c);

      // quad redistribution via DPP
      const float iv = quad_bcast<0>(act);
      const float gv = quad_bcast<2>(act);  // = kT * g
      const float fv = quad_bcast<1>(act);
      const float ov = quad_bcast<3>(act);

      cs = fmaf(fv, cs, iv * gv);           // kT-scaled cell state
      const float e2 = f_exp2(cs);          // = exp(-2c)
      const float r2 = f_rcp(1.0f + e2);
      h = ov * fmaf(2.0f, r2, -1.0f);       // = ov * tanh(c)
    }
    if (more) {
      xc0 = nx0; xc1 = nx1; xc2 = nx2; xc3 = nx3; xc4 = nx4;
      xc5 = nx5; xc6 = nx6; xc7 = nx7; xc8 = nx8;
    }
  }

  // epilogue: out[b][j] = sum_m h[m] * W_lin[j][m] + b_lin[j]
  const float wl = (q < 2) ? W_lin[q * H_ + m] : 0.0f;
  float p = h * wl;
  p += __shfl_xor(p, 4, 64);
  p += __shfl_xor(p, 8, 64);
  p += __shfl_xor(p, 16, 64);
  p += __shfl_xor(p, 32, 64);  // lanes with same q hold the q-group sum
  if (lane < 2) out[2 * b + lane] = p + b_lin[lane];
}

extern "C" void kernel_launch(void* const* d_in, const int* in_sizes, int n_in,
                              void* d_out, int out_size, void* d_ws,
                              size_t ws_size, hipStream_t stream) {
  const float* x = (const float*)d_in[0];
  const int* x_lens = (const int*)d_in[1];
  const float* W_ih = (const float*)d_in[2];
  const float* W_hh = (const float*)d_in[3];
  const float* b_ih = (const float*)d_in[4];
  const float* b_hh = (const float*)d_in[5];
  const float* W_lin = (const float*)d_in[6];
  const float* b_lin = (const float*)d_in[7];
  float* out = (float*)d_out;

  dim3 grid(B_);     // 2048 single-wave blocks: dynamic load balance,
  dim3 block(64);    // each wave stops at exactly its own length
  ParityLSTM_kernel<<<grid, block, 0, stream>>>(x, x_lens, W_ih, W_hh, b_ih,
                                                b_hh, W_lin, b_lin, out);
}